// Round 12
// baseline (132.879 us; speedup 1.0000x reference)
//
#include <hip/hip_runtime.h>
#include <math.h>

#define PI_F      3.14159265358979323846f
#define TWO_PI_F  6.28318530717958647692f
#define INV_2PI_F 0.15915494309189533577f

// Trip-2 loop — always fully unrolled at -O3; arrays promote to registers.
#define DO2 for (int u = 0; u < 2; ++u)

// ---- raw-instruction math helpers ----
__device__ __forceinline__ float fsqrt(float x)  { return __builtin_amdgcn_sqrtf(x); }
__device__ __forceinline__ float frcp(float x)   { return __builtin_amdgcn_rcpf(x); }
__device__ __forceinline__ float frsq(float x)   { return __builtin_amdgcn_rsqf(x); }
__device__ __forceinline__ float fexp2(float x)  { return __builtin_amdgcn_exp2f(x); }
__device__ __forceinline__ float flog2(float x)  { return __builtin_amdgcn_logf(x); }
__device__ __forceinline__ float fsin(float x)   { return __builtin_amdgcn_sinf(x * INV_2PI_F); }
__device__ __forceinline__ float fcos(float x)   { return __builtin_amdgcn_cosf(x * INV_2PI_F); }

// ============================================================================
// MATH — per-element expression trees VERBATIM from the R9/R11 passing kernel.
// A razor-edge pixel in the fixed dataset flips its |h_diff|>pi branch under
// sub-ulp perturbation (R3/R7/R8 all failed with identical absmax 0.2109375).
// This round changes ONLY statement interleaving across the two independent
// pixels (ILP), never the per-pixel op sequence — bit-identical by
// construction (FMA contraction is per-expression, order-independent).
// ============================================================================

__device__ __forceinline__ float fast_atan2(float y, float x) {
    float ax = fabsf(x), ay = fabsf(y);
    float mx = fmaxf(ax, ay), mn = fminf(ax, ay);
    float r = mn * frcp(mx);
    float s = r * r;
    float p = __fmaf_rn(s, -0.01172120f, 0.05265332f);
    p = __fmaf_rn(s, p, -0.11643287f);
    p = __fmaf_rn(s, p,  0.19354346f);
    p = __fmaf_rn(s, p, -0.33262347f);
    p = __fmaf_rn(s, p,  0.99997726f);
    float th = r * p;
    th = (ay > ax)   ? (1.57079632679f - th) : th;
    th = (x < 0.0f)  ? (PI_F - th)           : th;
    th = (y < 0.0f)  ? -th                   : th;
    th = (mx == 0.0f) ? 0.0f : th;            // atan2(0,0) = 0
    return th;
}

__device__ __forceinline__ float srgb_lin(float c) {
    float u = __fmaf_rn(c, 1.0f / 1.055f, 0.055f / 1.055f);
    float p = fexp2(2.4f * flog2(u));
    float l = c * (1.0f / 12.92f);
    return (c > 0.04045f) ? p : l;
}

__device__ __forceinline__ float labf(float t) {
    float cr = fexp2(0.333333333333f * flog2(t));
    float ln = __fmaf_rn(7.787f, t, 4.0f / 29.0f);
    return (t > 0.008856f) ? cr : ln;
}

__global__ __launch_bounds__(64) void ciede_kernel(
    const float* __restrict__ img1, const float* __restrict__ img2,
    float* __restrict__ out, int n2_total) {
    int idx = blockIdx.x * 64 + threadIdx.x;
    if (idx >= n2_total) return;

    const int PLANE2 = 131072;              // 512*512/2
    int n = idx >> 17;                      // batch index
    int j = idx & (PLANE2 - 1);             // float2 index within plane

    const float2* p1 = reinterpret_cast<const float2*>(img1) + (size_t)n * 3 * PLANE2;
    const float2* p2 = reinterpret_cast<const float2*>(img2) + (size_t)n * 3 * PLANE2;

    float2 r1v = p1[j], g1v = p1[j + PLANE2], b1v = p1[j + 2 * PLANE2];
    float2 r2v = p2[j], g2v = p2[j + PLANE2], b2v = p2[j + 2 * PLANE2];

    float R1[2]  = {r1v.x, r1v.y}, G1[2] = {g1v.x, g1v.y}, Bl1[2] = {b1v.x, b1v.y};
    float R2[2]  = {r2v.x, r2v.y}, G2[2] = {g2v.x, g2v.y}, Bl2[2] = {b2v.x, b2v.y};

    const float P25_7 = 6103515625.0f;  // 25^7

    // ---- rgb2lab (both images, both pixels), statement-interleaved ----
    float lr1[2], lg1[2], lb1[2], lr2[2], lg2[2], lb2[2];
    DO2 lr1[u] = srgb_lin(R1[u]);
    DO2 lg1[u] = srgb_lin(G1[u]);
    DO2 lb1[u] = srgb_lin(Bl1[u]);
    DO2 lr2[u] = srgb_lin(R2[u]);
    DO2 lg2[u] = srgb_lin(G2[u]);
    DO2 lb2[u] = srgb_lin(Bl2[u]);

    float xn1[2], yn1[2], zn1[2], xn2[2], yn2[2], zn2[2];
    DO2 xn1[u] = 0.4339463f * lr1[u] + 0.3762135f * lg1[u] + 0.1898252f * lb1[u];
    DO2 yn1[u] = 0.212671f  * lr1[u] + 0.71516f   * lg1[u] + 0.072169f  * lb1[u];
    DO2 zn1[u] = 0.0177566f * lr1[u] + 0.1094694f * lg1[u] + 0.8727056f * lb1[u];
    DO2 xn2[u] = 0.4339463f * lr2[u] + 0.3762135f * lg2[u] + 0.1898252f * lb2[u];
    DO2 yn2[u] = 0.212671f  * lr2[u] + 0.71516f   * lg2[u] + 0.072169f  * lb2[u];
    DO2 zn2[u] = 0.0177566f * lr2[u] + 0.1094694f * lg2[u] + 0.8727056f * lb2[u];

    float fx1[2], fy1[2], fz1[2], fx2[2], fy2[2], fz2[2];
    DO2 fx1[u] = labf(xn1[u]);
    DO2 fy1[u] = labf(yn1[u]);
    DO2 fz1[u] = labf(zn1[u]);
    DO2 fx2[u] = labf(xn2[u]);
    DO2 fy2[u] = labf(yn2[u]);
    DO2 fz2[u] = labf(zn2[u]);

    float L1[2], A1[2], B1[2], L2[2], A2[2], B2[2];
    DO2 L1[u] = __fmaf_rn(116.0f, fy1[u], -16.0f);
    DO2 A1[u] = 500.0f * (fx1[u] - fy1[u]);
    DO2 B1[u] = 200.0f * (fy1[u] - fz1[u]);
    DO2 L2[u] = __fmaf_rn(116.0f, fy2[u], -16.0f);
    DO2 A2[u] = 500.0f * (fx2[u] - fy2[u]);
    DO2 B2[u] = 200.0f * (fy2[u] - fz2[u]);

    float C1[2], C2[2], Cbar[2], c7[2], G[2], sG[2];
    DO2 C1[u] = fsqrt(__fmaf_rn(A1[u], A1[u], B1[u] * B1[u]));
    DO2 C2[u] = fsqrt(__fmaf_rn(A2[u], A2[u], B2[u] * B2[u]));
    DO2 Cbar[u] = 0.5f * (C1[u] + C2[u]);
    DO2 { float cb2 = Cbar[u] * Cbar[u]; c7[u] = cb2 * cb2 * cb2 * Cbar[u]; }
    DO2 G[u] = __fmaf_rn(-0.5f * c7[u], frsq(__fmaf_rn(c7[u], c7[u], __fmaf_rn(P25_7, c7[u], 1e-20f))), 0.5f);
    DO2 sG[u] = 1.0f + G[u];

    float a1p[2], a2p[2], C1p[2], C2p[2];
    DO2 a1p[u] = A1[u] * sG[u];
    DO2 a2p[u] = A2[u] * sG[u];
    DO2 C1p[u] = fsqrt(__fmaf_rn(a1p[u], a1p[u], B1[u] * B1[u]));
    DO2 C2p[u] = fsqrt(__fmaf_rn(a2p[u], a2p[u], B2[u] * B2[u]));

    // ---- hue block: literal reference semantics (R2/R4/R9/R11-verified). ----
    float h1[2], h2[2], CC[2], dH_term[2], Hbar[2];
    DO2 { float h = fast_atan2(B1[u], a1p[u]); h1[u] = (h < 0.0f) ? h + TWO_PI_F : h; }
    DO2 { float h = fast_atan2(B2[u], a2p[u]); h2[u] = (h < 0.0f) ? h + TWO_PI_F : h; }
    DO2 CC[u] = C1p[u] * C2p[u];
    DO2 {
        float h_diff = h2[u] - h1[u];
        float h_sum  = h1[u] + h2[u];
        bool cc0 = (CC[u] == 0.0f);
        float dH = (h_diff > PI_F) ? (h_diff - TWO_PI_F)
                 : ((h_diff < -PI_F) ? (h_diff + TWO_PI_F) : h_diff);
        if (cc0) dH = 0.0f;
        dH_term[u] = 2.0f * fsqrt(CC[u]) * fsin(0.5f * dH);
        bool mask = (!cc0) && (fabsf(h_diff) > PI_F);
        float Hb = h_sum;
        if (mask) Hb = (h_sum < TWO_PI_F) ? (h_sum + TWO_PI_F) : (h_sum - TWO_PI_F);
        if (cc0)  Hb = h_sum * 2.0f;
        Hbar[u] = Hb * 0.5f;
    }
    // ---- end hue block ----

    float SL[2], Cbarp[2], SC[2];
    DO2 { float Lbar = 0.5f * (L1[u] + L2[u]);
          float lt = Lbar - 50.0f;
          float tmp = lt * lt;
          SL[u] = __fmaf_rn(0.015f * tmp, frsq(20.0f + tmp), 1.0f); }
    DO2 Cbarp[u] = 0.5f * (C1p[u] + C2p[u]);
    DO2 SC[u] = __fmaf_rn(0.045f, Cbarp[u], 1.0f);

    float ch[2], sh[2], T[2], SH[2];
    DO2 ch[u] = fcos(Hbar[u]);
    DO2 sh[u] = fsin(Hbar[u]);
    DO2 {
        float c2 = __fmaf_rn(2.0f * ch[u], ch[u], -1.0f);
        float s2 = 2.0f * sh[u] * ch[u];
        float c3 = ch[u] * c2 - sh[u] * s2;
        float s3 = sh[u] * c2 + ch[u] * s2;
        float c4 = __fmaf_rn(2.0f * c2, c2, -1.0f);
        float s4 = 2.0f * s2 * c2;
        float T1 = __fmaf_rn(ch[u], 0.86602540378f, sh[u] * 0.5f);             // cos(H-30deg)
        float T3 = __fmaf_rn(c3, 0.99452189536f, -s3 * 0.10452846327f);        // cos(3H+6deg)
        float T4 = __fmaf_rn(c4, 0.45399049974f, s4 * 0.89100652419f);         // cos(4H-63deg)
        T[u] = 1.0f - 0.17f * T1 + 0.24f * c2 + 0.32f * T3 - 0.20f * T4;
    }
    DO2 SH[u] = __fmaf_rn(0.015f * Cbarp[u], T[u], 1.0f);

    float inv[2], L_term[2], C_term[2], H_term[2];
    DO2 { float PQ = SC[u] * SH[u];
          inv[u] = frcp(SL[u] * PQ);
          L_term[u] = (L2[u] - L1[u]) * PQ * inv[u]; }
    DO2 C_term[u] = (C2p[u] - C1p[u]) * (SL[u] * SH[u]) * inv[u];
    DO2 H_term[u] = dH_term[u] * (SL[u] * SC[u]) * inv[u];

    float Rc[2], sin2dt[2];
    DO2 { float cp2 = Cbarp[u] * Cbarp[u];
          float c7p = cp2 * cp2 * cp2 * Cbarp[u];
          Rc[u] = 2.0f * c7p * frsq(__fmaf_rn(c7p, c7p, __fmaf_rn(P25_7, c7p, 1e-20f))); }
    DO2 { float hd = __fmaf_rn(Hbar[u], 2.752769787f, -13.2123465f);
          float v = 1.04719755119f * fexp2(-(hd * hd));     // = 2*dtheta in (0, pi/3]
          float w = v * v;
          float sp = __fmaf_rn(w, -1.0f / 5040.0f, 1.0f / 120.0f);
          sp = __fmaf_rn(w, sp, -1.0f / 6.0f);
          sp = __fmaf_rn(w, sp, 1.0f);
          sin2dt[u] = v * sp; }

    float o[2];
    DO2 { float R_term = -sin2dt[u] * Rc[u] * C_term[u] * H_term[u];
          float dE2 = __fmaf_rn(L_term[u], L_term[u],
                      __fmaf_rn(C_term[u], C_term[u],
                      __fmaf_rn(H_term[u], H_term[u], R_term)));
          o[u] = fsqrt(fmaxf(dE2, 0.0f)) * 0.01f; }

    float2 ov; ov.x = o[0]; ov.y = o[1];
    reinterpret_cast<float2*>(out)[idx] = ov;
}

extern "C" void kernel_launch(void* const* d_in, const int* in_sizes, int n_in,
                              void* d_out, int out_size, void* d_ws, size_t ws_size,
                              hipStream_t stream) {
    const float* img1 = (const float*)d_in[0];
    const float* img2 = (const float*)d_in[1];
    float* out = (float*)d_out;

    int n2 = out_size / 2;           // 2,097,152 float2 work-items
    int grid = (n2 + 63) / 64;       // 32768 one-wave blocks
    ciede_kernel<<<grid, 64, 0, stream>>>(img1, img2, out, n2);
}

// Round 13
// 128.534 us; speedup vs baseline: 1.0338x; 1.0338x over previous
//
#include <hip/hip_runtime.h>
#include <math.h>

#define PI_F      3.14159265358979323846f
#define TWO_PI_F  6.28318530717958647692f
#define INV_2PI_F 0.15915494309189533577f

typedef float v2 __attribute__((ext_vector_type(2)));

// ---- scalar raw-instruction helpers ----
__device__ __forceinline__ float fsqrt(float x)  { return __builtin_amdgcn_sqrtf(x); }
__device__ __forceinline__ float frcp(float x)   { return __builtin_amdgcn_rcpf(x); }
__device__ __forceinline__ float frsq(float x)   { return __builtin_amdgcn_rsqf(x); }
__device__ __forceinline__ float fexp2(float x)  { return __builtin_amdgcn_exp2f(x); }
__device__ __forceinline__ float flog2(float x)  { return __builtin_amdgcn_logf(x); }
__device__ __forceinline__ float fsin(float x)   { return __builtin_amdgcn_sinf(x * INV_2PI_F); }
__device__ __forceinline__ float fcos(float x)   { return __builtin_amdgcn_cosf(x * INV_2PI_F); }

// ---- v2 helpers: elementwise; trans ops stay scalar per component ----
__device__ __forceinline__ v2 V(float s){ v2 r; r.x = s; r.y = s; return r; }
#if __has_builtin(__builtin_elementwise_fma)
__device__ __forceinline__ v2 vfma(v2 a, v2 b, v2 c){ return __builtin_elementwise_fma(a, b, c); }
#else
__device__ __forceinline__ v2 vfma(v2 a, v2 b, v2 c){ v2 r; r.x=__fmaf_rn(a.x,b.x,c.x); r.y=__fmaf_rn(a.y,b.y,c.y); return r; }
#endif
__device__ __forceinline__ v2 vmax0(v2 a){ v2 r; r.x=fmaxf(a.x,0.0f); r.y=fmaxf(a.y,0.0f); return r; }
__device__ __forceinline__ v2 vsqrt(v2 x){ v2 r; r.x=fsqrt(x.x); r.y=fsqrt(x.y); return r; }
__device__ __forceinline__ v2 vrcp (v2 x){ v2 r; r.x=frcp(x.x);  r.y=frcp(x.y);  return r; }
__device__ __forceinline__ v2 vrsq (v2 x){ v2 r; r.x=frsq(x.x);  r.y=frsq(x.y);  return r; }
__device__ __forceinline__ v2 vexp2(v2 x){ v2 r; r.x=fexp2(x.x); r.y=fexp2(x.y); return r; }
__device__ __forceinline__ v2 vsinr(v2 x){ v2 r; r.x=fsin(x.x); r.y=fsin(x.y); return r; }
__device__ __forceinline__ v2 vcosr(v2 x){ v2 r; r.x=fcos(x.x); r.y=fcos(x.y); return r; }

// ============================================================================
// UPSTREAM — scalar, VERBATIM from the R9/R11 passing kernel. A razor-edge
// pixel in the fixed dataset flips its |h_diff|>pi branch under sub-ulp
// perturbation (R3/R7/R8: identical absmax 0.2109375). DO NOT change
// expression trees, constants, or scalar form through the hue block.
// ============================================================================

__device__ __forceinline__ float fast_atan2(float y, float x) {
    float ax = fabsf(x), ay = fabsf(y);
    float mx = fmaxf(ax, ay), mn = fminf(ax, ay);
    float r = mn * frcp(mx);
    float s = r * r;
    float p = __fmaf_rn(s, -0.01172120f, 0.05265332f);
    p = __fmaf_rn(s, p, -0.11643287f);
    p = __fmaf_rn(s, p,  0.19354346f);
    p = __fmaf_rn(s, p, -0.33262347f);
    p = __fmaf_rn(s, p,  0.99997726f);
    float th = r * p;
    th = (ay > ax)   ? (1.57079632679f - th) : th;
    th = (x < 0.0f)  ? (PI_F - th)           : th;
    th = (y < 0.0f)  ? -th                   : th;
    th = (mx == 0.0f) ? 0.0f : th;            // atan2(0,0) = 0
    return th;
}

__device__ __forceinline__ float srgb_lin(float c) {
    float u = __fmaf_rn(c, 1.0f / 1.055f, 0.055f / 1.055f);
    float p = fexp2(2.4f * flog2(u));
    float l = c * (1.0f / 12.92f);
    return (c > 0.04045f) ? p : l;
}

__device__ __forceinline__ float labf(float t) {
    float cr = fexp2(0.333333333333f * flog2(t));
    float ln = __fmaf_rn(7.787f, t, 4.0f / 29.0f);
    return (t > 0.008856f) ? cr : ln;
}

__device__ __forceinline__ void rgb2lab(float r, float g, float b,
                                        float& L, float& A, float& B) {
    r = srgb_lin(r); g = srgb_lin(g); b = srgb_lin(b);
    float xn = 0.4339463f * r + 0.3762135f * g + 0.1898252f * b;
    float yn = 0.212671f  * r + 0.71516f   * g + 0.072169f  * b;
    float zn = 0.0177566f * r + 0.1094694f * g + 0.8727056f * b;
    float fx = labf(xn);
    float fy = labf(yn);
    float fz = labf(zn);
    L = __fmaf_rn(116.0f, fy, -16.0f);
    A = 500.0f * (fx - fy);
    B = 200.0f * (fy - fz);
}

// Scalar upstream through the hue block; exports smooth quantities.
__device__ __forceinline__ void upstream_px(float r1, float g1, float bl1,
                                            float r2, float g2, float bl2,
                                            float& L1o, float& L2o,
                                            float& C1po, float& C2po,
                                            float& dHto, float& Hbo) {
    float L1, A1, B1, L2, A2, B2;
    rgb2lab(r1, g1, bl1, L1, A1, B1);
    rgb2lab(r2, g2, bl2, L2, A2, B2);

    const float P25_7 = 6103515625.0f;  // 25^7

    float C1 = fsqrt(__fmaf_rn(A1, A1, B1 * B1));
    float C2 = fsqrt(__fmaf_rn(A2, A2, B2 * B2));
    float Cbar = 0.5f * (C1 + C2);
    float cb2 = Cbar * Cbar;
    float c7 = cb2 * cb2 * cb2 * Cbar;
    float G = __fmaf_rn(-0.5f * c7, frsq(__fmaf_rn(c7, c7, __fmaf_rn(P25_7, c7, 1e-20f))), 0.5f);
    float s = 1.0f + G;
    float a1p = A1 * s, a2p = A2 * s;
    float C1p = fsqrt(__fmaf_rn(a1p, a1p, B1 * B1));
    float C2p = fsqrt(__fmaf_rn(a2p, a2p, B2 * B2));

    // ---- hue block: literal reference semantics (R2/R4/R9/R11-verified). ----
    float h1 = fast_atan2(B1, a1p); h1 = (h1 < 0.0f) ? h1 + TWO_PI_F : h1;
    float h2 = fast_atan2(B2, a2p); h2 = (h2 < 0.0f) ? h2 + TWO_PI_F : h2;

    float h_diff = h2 - h1;
    float h_sum  = h1 + h2;
    float CC = C1p * C2p;
    bool cc0 = (CC == 0.0f);

    float dH = (h_diff > PI_F) ? (h_diff - TWO_PI_F)
             : ((h_diff < -PI_F) ? (h_diff + TWO_PI_F) : h_diff);
    if (cc0) dH = 0.0f;
    float dH_term = 2.0f * fsqrt(CC) * fsin(0.5f * dH);

    bool mask = (!cc0) && (fabsf(h_diff) > PI_F);
    float Hbar = h_sum;
    if (mask) Hbar = (h_sum < TWO_PI_F) ? (h_sum + TWO_PI_F) : (h_sum - TWO_PI_F);
    if (cc0)  Hbar = h_sum * 2.0f;
    Hbar *= 0.5f;
    // ---- end hue block ----

    L1o = L1; L2o = L2; C1po = C1p; C2po = C2p; dHto = dH_term; Hbo = Hbar;
}

// ============================================================================
// DOWNSTREAM — smooth in all inputs; packed v2 (v_pk_* f32) is safe here.
// Elementwise IEEE ops => ulp-identical to the scalar R11 path.
// ============================================================================

__global__ __launch_bounds__(64) void ciede_kernel(
    const float* __restrict__ img1, const float* __restrict__ img2,
    float* __restrict__ out, int n2_total) {
    int idx = blockIdx.x * 64 + threadIdx.x;
    if (idx >= n2_total) return;

    const int PLANE2 = 131072;              // 512*512/2
    int n = idx >> 17;                      // batch index
    int j = idx & (PLANE2 - 1);             // float2 index within plane

    const float2* p1 = reinterpret_cast<const float2*>(img1) + (size_t)n * 3 * PLANE2;
    const float2* p2 = reinterpret_cast<const float2*>(img2) + (size_t)n * 3 * PLANE2;

    float2 r1 = p1[j], g1 = p1[j + PLANE2], b1 = p1[j + 2 * PLANE2];
    float2 r2 = p2[j], g2 = p2[j + PLANE2], b2 = p2[j + 2 * PLANE2];

    const float P25_7 = 6103515625.0f;  // 25^7

    v2 L1, L2, C1p, C2p, dHt, Hb;
    {
        float a, b, c, d, e, f;
        upstream_px(r1.x, g1.x, b1.x, r2.x, g2.x, b2.x, a, b, c, d, e, f);
        L1.x = a; L2.x = b; C1p.x = c; C2p.x = d; dHt.x = e; Hb.x = f;
        upstream_px(r1.y, g1.y, b1.y, r2.y, g2.y, b2.y, a, b, c, d, e, f);
        L1.y = a; L2.y = b; C1p.y = c; C2p.y = d; dHt.y = e; Hb.y = f;
    }

    v2 Lbar = (L1 + L2) * 0.5f;
    v2 lt = Lbar - V(50.0f);
    v2 tmp = lt * lt;
    v2 SL = vfma(tmp * 0.015f, vrsq(V(20.0f) + tmp), V(1.0f));

    v2 Cbarp = (C1p + C2p) * 0.5f;
    v2 SC = vfma(V(0.045f), Cbarp, V(1.0f));

    v2 ch = vcosr(Hb);
    v2 sh = vsinr(Hb);
    v2 c2 = vfma(ch * 2.0f, ch, V(-1.0f));
    v2 s2 = sh * ch * 2.0f;
    v2 c3 = ch * c2 - sh * s2;
    v2 s3 = sh * c2 + ch * s2;
    v2 c4 = vfma(c2 * 2.0f, c2, V(-1.0f));
    v2 s4 = s2 * c2 * 2.0f;
    v2 T1 = vfma(ch, V(0.86602540378f), sh * 0.5f);              // cos(H-30deg)
    v2 T3 = vfma(c3, V(0.99452189536f), s3 * -0.10452846327f);   // cos(3H+6deg)
    v2 T4 = vfma(c4, V(0.45399049974f), s4 * 0.89100652419f);    // cos(4H-63deg)
    v2 T = V(1.0f) - T1 * 0.17f + c2 * 0.24f + T3 * 0.32f - T4 * 0.20f;
    v2 SH = vfma(Cbarp * 0.015f, T, V(1.0f));

    v2 PQ  = SC * SH;
    v2 inv = vrcp(SL * PQ);
    v2 L_term = (L2 - L1) * PQ * inv;
    v2 C_term = (C2p - C1p) * (SL * SH) * inv;
    v2 H_term = dHt * (SL * SC) * inv;

    v2 cp2 = Cbarp * Cbarp;
    v2 c7p = cp2 * cp2 * cp2 * Cbarp;
    v2 Rc = c7p * 2.0f * vrsq(vfma(c7p, c7p, vfma(V(P25_7), c7p, V(1e-20f))));

    v2 hd = vfma(Hb, V(2.752769787f), V(-13.2123465f));
    v2 vv = vexp2(-(hd * hd)) * 1.04719755119f;          // = 2*dtheta in (0, pi/3]
    v2 w  = vv * vv;
    v2 sp = vfma(w, V(-1.0f / 5040.0f), V(1.0f / 120.0f));
    sp = vfma(w, sp, V(-1.0f / 6.0f));
    sp = vfma(w, sp, V(1.0f));
    v2 sin2dt = vv * sp;
    v2 R_term = -(sin2dt * Rc * C_term * H_term);

    v2 dE2 = vfma(L_term, L_term, vfma(C_term, C_term, vfma(H_term, H_term, R_term)));
    v2 o = vsqrt(vmax0(dE2)) * 0.01f;

    float2 ov; ov.x = o.x; ov.y = o.y;
    reinterpret_cast<float2*>(out)[idx] = ov;
}

extern "C" void kernel_launch(void* const* d_in, const int* in_sizes, int n_in,
                              void* d_out, int out_size, void* d_ws, size_t ws_size,
                              hipStream_t stream) {
    const float* img1 = (const float*)d_in[0];
    const float* img2 = (const float*)d_in[1];
    float* out = (float*)d_out;

    int n2 = out_size / 2;           // 2,097,152 float2 work-items
    int grid = (n2 + 63) / 64;       // 32768 one-wave blocks
    ciede_kernel<<<grid, 64, 0, stream>>>(img1, img2, out, n2);
}